// Round 15
// baseline (184.900 us; speedup 1.0000x reference)
//
#include <hip/hip_runtime.h>
#include <hip/hip_bf16.h>

typedef __attribute__((ext_vector_type(8))) short bf16x8;
typedef __attribute__((ext_vector_type(4))) float f32x4;

static __device__ __forceinline__ unsigned short f2bf(float f) {
    unsigned u = __builtin_bit_cast(unsigned, f);
    unsigned rounding = 0x7fffu + ((u >> 16) & 1u);
    u += rounding;
    return (unsigned short)(u >> 16);
}

static __device__ __forceinline__ void async_copy16(const void* g, void* l) {
    __builtin_amdgcn_global_load_lds(
        (const __attribute__((address_space(1))) unsigned int*)g,
        (__attribute__((address_space(3))) unsigned int*)l,
        16, 0, 0);
}

#define BARRIER() __builtin_amdgcn_s_barrier()
#define VMCNT(N) do { asm volatile("s_waitcnt vmcnt(" #N ")" ::: "memory"); \
                      __builtin_amdgcn_sched_barrier(0); } while (0)
#define VM0() VMCNT(0)
#define LGKM0()  do { asm volatile("s_waitcnt lgkmcnt(0)" ::: "memory"); \
                      __builtin_amdgcn_sched_barrier(0); } while (0)

// fast erf-gelu via tanh approximation (|err| <= ~3e-3, threshold margin 0.07+)
static __device__ __forceinline__ float fast_gelu(float y) {
    float u = 0.7978845608028654f * y * (1.0f + 0.044715f * y * y);
    float au = fminf(fabsf(u), 9.0f);
    float e = __expf(-2.0f * au);
    float th = (1.0f - e) * __builtin_amdgcn_rcpf(1.0f + e);
    th = (u < 0.0f) ? -th : th;
    return 0.5f * y * (1.0f + th);
}

// ---------------- merged prep: LN(+bf16 cast) and W->Wt transpose-cast --------
__global__ __launch_bounds__(256) void prep_kernel(
    const float* __restrict__ x, const float* __restrict__ gamma,
    const float* __restrict__ beta, unsigned short* __restrict__ Aout,
    const float* __restrict__ W, unsigned short* __restrict__ Wt) {
    __shared__ float smem[33 * 32];
    const int b = blockIdx.x;
    const int t = threadIdx.x;

    if (b < 16384) {
        const int row = b;
        const float4 v = ((const float4*)(x + (size_t)row * 1024))[t];
        float s  = v.x + v.y + v.z + v.w;
        float ss = v.x * v.x + v.y * v.y + v.z * v.z + v.w * v.w;
        #pragma unroll
        for (int off = 32; off; off >>= 1) {
            s  += __shfl_down(s, off);
            ss += __shfl_down(ss, off);
        }
        const int wid = t >> 6, lane = t & 63;
        if (lane == 0) { smem[wid] = s; smem[wid + 4] = ss; }
        __syncthreads();
        if (t == 0) {
            float S  = smem[0] + smem[1] + smem[2] + smem[3];
            float SS = smem[4] + smem[5] + smem[6] + smem[7];
            float mu = S * (1.0f / 1024.0f);
            float var = SS * (1.0f / 1024.0f) - mu * mu;
            smem[0] = mu;
            smem[1] = rsqrtf(var + 1e-7f);
        }
        __syncthreads();
        const float mu = smem[0], rs = smem[1];
        const float4 g = ((const float4*)gamma)[t];
        const float4 be = ((const float4*)beta)[t];
        ushort4 pk;
        pk.x = f2bf((v.x - mu) * rs * g.x + be.x);
        pk.y = f2bf((v.y - mu) * rs * g.y + be.y);
        pk.z = f2bf((v.z - mu) * rs * g.z + be.z);
        pk.w = f2bf((v.w - mu) * rs * g.w + be.w);
        ((ushort4*)(Aout + (size_t)row * 1024))[t] = pk;
    } else {
        const int r = b - 16384;            // 4096 tiles: bx 0..127, by 0..31
        const int bx = r & 127;
        const int by = r >> 7;
        float (*tile)[33] = (float(*)[33])smem;
        const int tx = t & 31;
        const int ty = t >> 5;
        #pragma unroll
        for (int i = 0; i < 4; ++i) {
            int k = by * 32 + ty + i * 8;
            tile[ty + i * 8][tx] = W[(size_t)k * 4096 + bx * 32 + tx];
        }
        __syncthreads();
        #pragma unroll
        for (int i = 0; i < 4; ++i) {
            int n = bx * 32 + ty + i * 8;
            Wt[(size_t)n * 1024 + by * 32 + tx] = f2bf(tile[tx][ty + i * 8]);
        }
    }
}

// ---------------- GEMM 256x256, BK=64, dbuf 128KB, 4-phase C-quadrant ----------
// m201-style cadence. Per kt, phases (mh,nh): P1(m0,n0) 12 reads, P2(m0,n1) 4,
// P3(m1,n1) 8, P4(m1,n0) 0 (register reuse). Each phase stages ONE 16KB region
// of kt+1 into the other buffer: P1:Am0, P2:Bn0, P3:Bn1, P4:Am1.
// Regions interleaved to match phase reads: Am0 = A rows {0-63,128-191},
// Am1 = {64-127,192-255}, Bn0 = B rows {0-31,64-95,128-159,192-223}, Bn1 = +32.
// Wait ledger (in-order retire; 2 loads/region/thread; steady kt entered with
// [Bn1(kt),Am1(kt)] = 4 outstanding):
//  end-P1: vmcnt(4) -> retires Bn1(kt)            [6 -> 4]
//  end-P2: vmcnt(4) -> retires Am1(kt)            [6 -> 4]
//  end-P3: no wait                                 [6]
//  end-P4: vmcnt(4) -> retires Am0,Bn0(kt+1)      [8 -> 4]   never drains to 0
// kt=15 (no staging): end-P1 vmcnt(2), end-P2 vmcnt(0), none after.
// Buffer safety: stage into buf_c only at P1 of the NEXT kt, >=2 barriers
// after buf_c's last read (P3). Epilogue stores only after all waits done.
__global__ __launch_bounds__(512, 1) void gemm_kernel(
    const unsigned short* __restrict__ A, const unsigned short* __restrict__ Wt,
    const float* __restrict__ bias, float* __restrict__ out) {
    __shared__ char lds_mem[131072];   // [2 bufs][A 32KB | B 32KB]

    const int bid = blockIdx.x;        // 1024 blocks, %8==0 -> bijective swizzle
    const int swz = (bid & 7) * 128 + (bid >> 3);
    const int bm = swz >> 4;           // 0..63
    const int bn = swz & 15;           // 0..15

    const int t = threadIdx.x;
    const int lane = t & 63;
    const int wid = t >> 6;            // 0..7
    const int wm = wid >> 2;           // 0..1  (M half)
    const int wn = wid & 3;            // 0..3  (N quarter)
    const int lrow = lane & 15;
    const int lk = lane >> 4;          // 0..3

    // staging thread coords
    const int sra = t >> 3;                                   // 0..63
    const int srb = ((t >> 3) & 31) + (((t >> 3) >> 5) << 6); // 0..31, 64..95
    const int sch = t & 7;
    const int sgc = sch ^ (sra & 7);   // (t>>3)&7 for both A and B rows
    const unsigned short* gAb = A  + (size_t)(bm * 256) * 1024 + sgc * 8;
    const unsigned short* gBb = Wt + (size_t)(bn * 256) * 1024 + sgc * 8;

    auto stAm0 = [&](int kt, char* buf) {
        #pragma unroll
        for (int j = 0; j < 2; ++j) {
            const int row = j * 128 + sra;
            async_copy16(gAb + (size_t)row * 1024 + kt * 64, buf + row * 128 + sch * 16);
        }
    };
    auto stAm1 = [&](int kt, char* buf) {
        #pragma unroll
        for (int j = 0; j < 2; ++j) {
            const int row = j * 128 + 64 + sra;
            async_copy16(gAb + (size_t)row * 1024 + kt * 64, buf + row * 128 + sch * 16);
        }
    };
    auto stBn0 = [&](int kt, char* buf) {
        #pragma unroll
        for (int j = 0; j < 2; ++j) {
            const int row = j * 128 + srb;
            async_copy16(gBb + (size_t)row * 1024 + kt * 64, buf + 32768 + row * 128 + sch * 16);
        }
    };
    auto stBn1 = [&](int kt, char* buf) {
        #pragma unroll
        for (int j = 0; j < 2; ++j) {
            const int row = j * 128 + 32 + srb;
            async_copy16(gBb + (size_t)row * 1024 + kt * 64, buf + 32768 + row * 128 + sch * 16);
        }
    };

    // read-side swizzle: chunk c of frag-row r -> slot (c ^ (r&7)); r&7 == lrow&7
    const int ck0 = ((lk) ^ (lrow & 7)) * 16;
    const int ck1 = ((4 + lk) ^ (lrow & 7)) * 16;
    const int aBase = (wm * 128 + lrow) * 128;           // + mi*16*128, mi 0..7
    const int bBase = 32768 + (wn * 64 + lrow) * 128;    // + (nh*32+ni*16)*128

    char* lds0 = lds_mem;
    char* lds1 = lds_mem + 65536;

    f32x4 acc[8][4];   // [row mi][col j], col offset = j*16 (j = nh*2+ni)
    #pragma unroll
    for (int a = 0; a < 8; ++a)
        #pragma unroll
        for (int j = 0; j < 4; ++j) acc[a][j] = (f32x4)0.0f;

    float bv[4];
    #pragma unroll
    for (int j = 0; j < 4; ++j) bv[j] = bias[bn * 256 + wn * 64 + j * 16 + lrow];

    // prologue: all 4 regions of kt=0 -> buf0; full drain once
    stAm0(0, lds0); stBn0(0, lds0); stBn1(0, lds0); stAm1(0, lds0);
    VM0();
    BARRIER();

    const int NKT = 16;
    for (int kt = 0; kt < NKT; ++kt) {
        char* cbuf = (kt & 1) ? lds1 : lds0;
        char* nbuf = (kt & 1) ? lds0 : lds1;
        const bool hn = (kt + 1 < NKT);
        const int ktn = kt + 1;

        bf16x8 af[4][2], bf0[2][2], bf1[2][2];

        // ---- P1 (m0,n0): read A m0 (8) + B n0 (4); stage Am0(kt+1)
        #pragma unroll
        for (int mi = 0; mi < 4; ++mi) {
            const char* p = cbuf + aBase + mi * 16 * 128;
            af[mi][0] = *(const bf16x8*)(p + ck0);
            af[mi][1] = *(const bf16x8*)(p + ck1);
        }
        #pragma unroll
        for (int ni = 0; ni < 2; ++ni) {
            const char* p = cbuf + bBase + ni * 16 * 128;
            bf0[ni][0] = *(const bf16x8*)(p + ck0);
            bf0[ni][1] = *(const bf16x8*)(p + ck1);
        }
        if (hn) stAm0(ktn, nbuf);
        BARRIER();
        LGKM0();
        __builtin_amdgcn_s_setprio(1);
        #pragma unroll
        for (int mi = 0; mi < 4; ++mi)
            #pragma unroll
            for (int ni = 0; ni < 2; ++ni) {
                acc[mi][ni] = __builtin_amdgcn_mfma_f32_16x16x32_bf16(af[mi][0], bf0[ni][0], acc[mi][ni], 0, 0, 0);
                acc[mi][ni] = __builtin_amdgcn_mfma_f32_16x16x32_bf16(af[mi][1], bf0[ni][1], acc[mi][ni], 0, 0, 0);
            }
        __builtin_amdgcn_s_setprio(0);
        if (hn) { VMCNT(4); } else { VMCNT(2); }   // P2 needs Bn1(kt)
        BARRIER();

        // ---- P2 (m0,n1): read B n1 (4); stage Bn0(kt+1); A m0 reused
        #pragma unroll
        for (int ni = 0; ni < 2; ++ni) {
            const char* p = cbuf + bBase + (32 + ni * 16) * 128;
            bf1[ni][0] = *(const bf16x8*)(p + ck0);
            bf1[ni][1] = *(const bf16x8*)(p + ck1);
        }
        if (hn) stBn0(ktn, nbuf);
        BARRIER();
        LGKM0();
        __builtin_amdgcn_s_setprio(1);
        #pragma unroll
        for (int mi = 0; mi < 4; ++mi)
            #pragma unroll
            for (int ni = 0; ni < 2; ++ni) {
                acc[mi][2 + ni] = __builtin_amdgcn_mfma_f32_16x16x32_bf16(af[mi][0], bf1[ni][0], acc[mi][2 + ni], 0, 0, 0);
                acc[mi][2 + ni] = __builtin_amdgcn_mfma_f32_16x16x32_bf16(af[mi][1], bf1[ni][1], acc[mi][2 + ni], 0, 0, 0);
            }
        __builtin_amdgcn_s_setprio(0);
        if (hn) { VMCNT(4); } else { VM0(); }      // P3 needs Am1(kt)
        BARRIER();

        // ---- P3 (m1,n1): read A m1 (8); stage Bn1(kt+1); B n1 reused
        #pragma unroll
        for (int mi = 0; mi < 4; ++mi) {
            const char* p = cbuf + aBase + (64 + mi * 16) * 128;
            af[mi][0] = *(const bf16x8*)(p + ck0);
            af[mi][1] = *(const bf16x8*)(p + ck1);
        }
        if (hn) stBn1(ktn, nbuf);
        BARRIER();
        LGKM0();
        __builtin_amdgcn_s_setprio(1);
        #pragma unroll
        for (int mi = 0; mi < 4; ++mi)
            #pragma unroll
            for (int ni = 0; ni < 2; ++ni) {
                acc[4 + mi][2 + ni] = __builtin_amdgcn_mfma_f32_16x16x32_bf16(af[mi][0], bf1[ni][0], acc[4 + mi][2 + ni], 0, 0, 0);
                acc[4 + mi][2 + ni] = __builtin_amdgcn_mfma_f32_16x16x32_bf16(af[mi][1], bf1[ni][1], acc[4 + mi][2 + ni], 0, 0, 0);
            }
        __builtin_amdgcn_s_setprio(0);
        BARRIER();                                  // no vmcnt (P4 reads nothing)

        // ---- P4 (m1,n0): no reads; stage Am1(kt+1); A m1 + B n0 reused
        if (hn) stAm1(ktn, nbuf);
        BARRIER();
        __builtin_amdgcn_s_setprio(1);
        #pragma unroll
        for (int mi = 0; mi < 4; ++mi)
            #pragma unroll
            for (int ni = 0; ni < 2; ++ni) {
                acc[4 + mi][ni] = __builtin_amdgcn_mfma_f32_16x16x32_bf16(af[mi][0], bf0[ni][0], acc[4 + mi][ni], 0, 0, 0);
                acc[4 + mi][ni] = __builtin_amdgcn_mfma_f32_16x16x32_bf16(af[mi][1], bf0[ni][1], acc[4 + mi][ni], 0, 0, 0);
            }
        __builtin_amdgcn_s_setprio(0);
        if (hn) {
            VMCNT(4);    // P1(kt+1) needs Am0,Bn0(kt+1); Bn1,Am1 stay in flight
            BARRIER();
        }
    }

    // ---- epilogue: bias + fast gelu, fp32 store
    #pragma unroll
    for (int mi = 0; mi < 8; ++mi) {
        const int row0 = bm * 256 + wm * 128 + mi * 16 + lk * 4;
        #pragma unroll
        for (int j = 0; j < 4; ++j) {
            const int col = bn * 256 + wn * 64 + j * 16 + lrow;
            #pragma unroll
            for (int r = 0; r < 4; ++r) {
                float y = acc[mi][j][r] + bv[j];
                out[(size_t)(row0 + r) * 4096 + col] = fast_gelu(y);
            }
        }
    }
}

extern "C" void kernel_launch(void* const* d_in, const int* in_sizes, int n_in,
                              void* d_out, int out_size, void* d_ws, size_t ws_size,
                              hipStream_t stream) {
    const float* hidden = (const float*)d_in[0];
    const float* gamma  = (const float*)d_in[1];
    const float* beta   = (const float*)d_in[2];
    const float* W      = (const float*)d_in[3];
    const float* bias   = (const float*)d_in[4];
    float* out = (float*)d_out;

    unsigned short* Abf = (unsigned short*)d_ws;
    unsigned short* Wt  = (unsigned short*)((char*)d_ws + (size_t)16384 * 1024 * 2);

    prep_kernel<<<16384 + 4096, 256, 0, stream>>>(hidden, gamma, beta, Abf, W, Wt);
    gemm_kernel<<<1024, 512, 0, stream>>>(Abf, Wt, bias, out);
}